// Round 1
// baseline (561.137 us; speedup 1.0000x reference)
//
#include <hip/hip_runtime.h>

typedef unsigned short u16;
typedef unsigned int   u32;
typedef __attribute__((ext_vector_type(4))) float f32x4;
typedef __attribute__((ext_vector_type(4))) u32   u32x4;
typedef __attribute__((ext_vector_type(8))) __bf16 bf16x8;

constexpr int NV   = 50000;   // vertices
constexpr int NE   = 25000;   // hyperedges
constexpr int NNZp = 400000;  // incidence pairs
constexpr int D    = 512;     // d_in == d_out
constexpr int MP   = 50048;   // NV padded to 128 (391*128)

static __device__ __forceinline__ u16 f2bf(float f) {
  u32 u = __float_as_uint(f);
  u32 r = (u + 0x7fffu + ((u >> 16) & 1u)) >> 16;  // RNE
  return (u16)r;
}
static __device__ __forceinline__ float bf2f(u32 bits16) {
  return __uint_as_float(bits16 << 16);
}
static __device__ __forceinline__ u32 pk2(float a, float b) {
  return (u32)f2bf(a) | ((u32)f2bf(b) << 16);
}

// ---------------- zero segment counters ----------------
__global__ void zero_kernel(int* cntE, int* cntV) {
  int i = blockIdx.x * 256 + threadIdx.x;
  if (i < NE) cntE[i] = 0;
  if (i < NV) cntV[i] = 0;
}

// ---------------- histogram of incidence pairs ----------------
__global__ void hist_kernel(const int* __restrict__ vidx, const int* __restrict__ eidx,
                            int* cntE, int* cntV) {
  int i = blockIdx.x * 256 + threadIdx.x;
  if (i < NNZp) {
    atomicAdd(&cntE[eidx[i]], 1);
    atomicAdd(&cntV[vidx[i]], 1);
  }
}

// ---------------- exclusive scan (block 0: edges, block 1: vertices) ----------------
__global__ __launch_bounds__(1024) void scan_kernel(
    const int* __restrict__ cntE, int* offE, int* curE,
    const int* __restrict__ cntV, int* offV, int* curV) {
  const int* cnt; int* off; int* cur; int len;
  if (blockIdx.x == 0) { cnt = cntE; off = offE; cur = curE; len = NE; }
  else                 { cnt = cntV; off = offV; cur = curV; len = NV; }
  int t = threadIdx.x;
  int chunk = (len + 1023) >> 10;
  int lo = t * chunk, hi = min(lo + chunk, len);
  int s = 0;
  for (int i = lo; i < hi; i++) s += cnt[i];
  __shared__ int sm[1024];
  sm[t] = s;
  __syncthreads();
  // Hillis-Steele inclusive scan over 1024 partials
  for (int dstep = 1; dstep < 1024; dstep <<= 1) {
    int add = (t >= dstep) ? sm[t - dstep] : 0;
    __syncthreads();
    sm[t] += add;
    __syncthreads();
  }
  int run = sm[t] - s;  // exclusive prefix of this thread's chunk
  for (int i = lo; i < hi; i++) { off[i] = run; cur[i] = run; run += cnt[i]; }
}

// ---------------- scatter pairs into CSR ----------------
__global__ void scatter_kernel(const int* __restrict__ vidx, const int* __restrict__ eidx,
                               int* curE, int* curV, int* csr_ev, int* csr_ve) {
  int i = blockIdx.x * 256 + threadIdx.x;
  if (i < NNZp) {
    int e = eidx[i], v = vidx[i];
    csr_ev[atomicAdd(&curE[e], 1)] = v;  // edge -> member vertices
    csr_ve[atomicAdd(&curV[v], 1)] = e;  // vertex -> incident edges
  }
}

// ---------------- GEMM: Xp = X @ W^T (bf16 MFMA, fused fp32->bf16 cast) -------------
// A = X [NV][D] fp32, B = W [D][D] fp32 (row = out channel, K-major => B^T layout),
// C = Xp [MP][D] bf16. 128x128 tile, BK=32, 4 waves of 64x64, 16x16x32 MFMA.
__global__ __launch_bounds__(256) void gemm_kernel(const float* __restrict__ A,
                                                   const float* __restrict__ B,
                                                   u16* __restrict__ C) {
  __shared__ u16 sA[128 * 32];
  __shared__ u16 sB[128 * 32];
  const int tid  = threadIdx.x;
  const int lane = tid & 63;
  const int wave = tid >> 6;
  const int bm = blockIdx.y * 128;
  const int bn = blockIdx.x * 128;
  const int r0 = tid >> 2;          // 0..63 staging row
  const int k8 = (tid & 3) * 8;     // 0/8/16/24 staging k-offset
  const int wm = (wave >> 1) * 64;
  const int wn = (wave & 1) * 64;
  const int lr = lane & 15;
  const int lk = (lane >> 4) * 8;
  const bool v1 = (bm + r0 + 64) < NV;  // only the upper A-chunk can run off the end

  f32x4 acc[4][4] = {};

  for (int kt = 0; kt < D; kt += 32) {
    const float* a0p = A + (size_t)(bm + r0) * D + kt + k8;
    const float* a1p = a0p + (size_t)64 * D;
    const float* b0p = B + (size_t)(bn + r0) * D + kt + k8;
    const float* b1p = b0p + (size_t)64 * D;
    f32x4 a0l = *(const f32x4*)a0p;
    f32x4 a0h = *(const f32x4*)(a0p + 4);
    f32x4 a1l = {}, a1h = {};
    if (v1) { a1l = *(const f32x4*)a1p; a1h = *(const f32x4*)(a1p + 4); }
    f32x4 b0l = *(const f32x4*)b0p;
    f32x4 b0h = *(const f32x4*)(b0p + 4);
    f32x4 b1l = *(const f32x4*)b1p;
    f32x4 b1h = *(const f32x4*)(b1p + 4);

    u32x4 pa0 = { pk2(a0l[0], a0l[1]), pk2(a0l[2], a0l[3]), pk2(a0h[0], a0h[1]), pk2(a0h[2], a0h[3]) };
    u32x4 pa1 = { pk2(a1l[0], a1l[1]), pk2(a1l[2], a1l[3]), pk2(a1h[0], a1h[1]), pk2(a1h[2], a1h[3]) };
    u32x4 pb0 = { pk2(b0l[0], b0l[1]), pk2(b0l[2], b0l[3]), pk2(b0h[0], b0h[1]), pk2(b0h[2], b0h[3]) };
    u32x4 pb1 = { pk2(b1l[0], b1l[1]), pk2(b1l[2], b1l[3]), pk2(b1h[0], b1h[1]), pk2(b1h[2], b1h[3]) };

    __syncthreads();  // protect LDS against previous iteration's readers
    *(u32x4*)&sA[(r0)      * 32 + k8] = pa0;
    *(u32x4*)&sA[(r0 + 64) * 32 + k8] = pa1;
    *(u32x4*)&sB[(r0)      * 32 + k8] = pb0;
    *(u32x4*)&sB[(r0 + 64) * 32 + k8] = pb1;
    __syncthreads();

    bf16x8 af[4], bfr[4];
#pragma unroll
    for (int i = 0; i < 4; i++) af[i]  = *(const bf16x8*)&sA[(wm + i * 16 + lr) * 32 + lk];
#pragma unroll
    for (int j = 0; j < 4; j++) bfr[j] = *(const bf16x8*)&sB[(wn + j * 16 + lr) * 32 + lk];
#pragma unroll
    for (int i = 0; i < 4; i++)
#pragma unroll
      for (int j = 0; j < 4; j++)
        acc[i][j] = __builtin_amdgcn_mfma_f32_16x16x32_bf16(af[i], bfr[j], acc[i][j], 0, 0, 0);
  }

  // C/D layout (16x16): col = lane&15, row = (lane>>4)*4 + reg
#pragma unroll
  for (int i = 0; i < 4; i++)
#pragma unroll
    for (int r = 0; r < 4; r++) {
      int row = bm + wm + i * 16 + (lane >> 4) * 4 + r;
      u16* crow = C + (size_t)row * D + bn + wn + lr;
#pragma unroll
      for (int j = 0; j < 4; j++) crow[j * 16] = f2bf(acc[i][j][r]);
    }
}

// ---------------- stage 1: vertex -> hyperedge (mean via degE, * Wdiag) --------------
__global__ __launch_bounds__(256) void stage1_kernel(
    const u16* __restrict__ Xp, const int* __restrict__ offE, const int* __restrict__ cntE,
    const int* __restrict__ csr_ev, const float* __restrict__ degE,
    const float* __restrict__ Wdiag, u16* __restrict__ Xe) {
  int e = blockIdx.x;
  int t = threadIdx.x;
  int start = offE[e], cnt = cntE[e];
  __shared__ int sm[256];
  float ax = 0.f, ay = 0.f;
  int col = t * 2;
  for (int base = 0; base < cnt; base += 256) {
    __syncthreads();
    if (base + t < cnt) sm[t] = csr_ev[start + base + t];
    __syncthreads();
    int kmax = min(256, cnt - base);
#pragma unroll 4
    for (int k = 0; k < kmax; k++) {
      int v = sm[k];
      u32 p = *(const u32*)(Xp + (size_t)v * D + col);
      ax += bf2f(p & 0xffffu);
      ay += bf2f(p >> 16);
    }
  }
  float s = degE[e] * Wdiag[e];
  ((u32*)Xe)[e * 256 + t] = pk2(ax * s, ay * s);
}

// ---------------- stage 2: hyperedge -> vertex (normalized by degV) ------------------
__global__ __launch_bounds__(256) void stage2_kernel(
    const u16* __restrict__ Xe, const int* __restrict__ offV, const int* __restrict__ cntV,
    const int* __restrict__ csr_ve, const float* __restrict__ degV, float* __restrict__ out) {
  int v = blockIdx.x;
  int t = threadIdx.x;
  int start = offV[v], cnt = cntV[v];
  __shared__ int sm[256];
  float ax = 0.f, ay = 0.f;
  int col = t * 2;
  for (int base = 0; base < cnt; base += 256) {
    __syncthreads();
    if (base + t < cnt) sm[t] = csr_ve[start + base + t];
    __syncthreads();
    int kmax = min(256, cnt - base);
#pragma unroll 4
    for (int k = 0; k < kmax; k++) {
      int e = sm[k];
      u32 p = *(const u32*)(Xe + (size_t)e * D + col);
      ax += bf2f(p & 0xffffu);
      ay += bf2f(p >> 16);
    }
  }
  float s = degV[v];
  float2 r;
  r.x = ax * s;
  r.y = ay * s;
  ((float2*)out)[v * 256 + t] = r;
}

extern "C" void kernel_launch(void* const* d_in, const int* in_sizes, int n_in,
                              void* d_out, int out_size, void* d_ws, size_t ws_size,
                              hipStream_t stream) {
  const float* X     = (const float*)d_in[0];
  const float* W     = (const float*)d_in[1];
  const float* degE  = (const float*)d_in[2];
  const float* degV  = (const float*)d_in[3];
  const float* Wdiag = (const float*)d_in[4];
  const int*   vidx  = (const int*)d_in[5];
  const int*   eidx  = (const int*)d_in[6];
  float* out = (float*)d_out;

  // workspace carve (all 256B aligned); total ~81 MB
  char* p = (char*)d_ws;
  auto take = [&](size_t bytes) { char* r = p; p += (bytes + 255) & ~(size_t)255; return r; };
  u16* Xp     = (u16*)take((size_t)MP * D * 2);   // 51.2 MB bf16 projected features
  u16* Xe     = (u16*)take((size_t)NE * D * 2);   // 25.6 MB bf16 edge features
  int* cntE   = (int*)take((size_t)NE * 4);
  int* offE   = (int*)take((size_t)NE * 4);
  int* curE   = (int*)take((size_t)NE * 4);
  int* cntV   = (int*)take((size_t)NV * 4);
  int* offV   = (int*)take((size_t)NV * 4);
  int* curV   = (int*)take((size_t)NV * 4);
  int* csr_ev = (int*)take((size_t)NNZp * 4);
  int* csr_ve = (int*)take((size_t)NNZp * 4);

  zero_kernel   <<<(NV + 255) / 256, 256, 0, stream>>>(cntE, cntV);
  hist_kernel   <<<(NNZp + 255) / 256, 256, 0, stream>>>(vidx, eidx, cntE, cntV);
  scan_kernel   <<<2, 1024, 0, stream>>>(cntE, offE, curE, cntV, offV, curV);
  scatter_kernel<<<(NNZp + 255) / 256, 256, 0, stream>>>(vidx, eidx, curE, curV, csr_ev, csr_ve);
  gemm_kernel   <<<dim3(D / 128, MP / 128), 256, 0, stream>>>(X, W, Xp);
  stage1_kernel <<<NE, 256, 0, stream>>>(Xp, offE, cntE, csr_ev, degE, Wdiag, Xe);
  stage2_kernel <<<NV, 256, 0, stream>>>(Xe, offV, cntV, csr_ve, degV, out);
}

// Round 2
// 441.552 us; speedup vs baseline: 1.2708x; 1.2708x over previous
//
#include <hip/hip_runtime.h>

typedef unsigned short u16;
typedef unsigned int   u32;
typedef __attribute__((ext_vector_type(4))) float f32x4;
typedef __attribute__((ext_vector_type(4))) u32   u32x4;
typedef __attribute__((ext_vector_type(8))) __bf16 bf16x8;

constexpr int NV   = 50000;   // vertices
constexpr int NE   = 25000;   // hyperedges
constexpr int NNZp = 400000;  // incidence pairs
constexpr int D    = 512;     // d_in == d_out
constexpr int MP   = 50048;   // NV padded to 128 (391*128)
constexpr int NBE  = 25;      // scan blocks for E (1024 elems each)
constexpr int NBV  = 49;      // scan blocks for V

static __device__ __forceinline__ u16 f2bf(float f) {
  u32 u = __float_as_uint(f);
  u32 r = (u + 0x7fffu + ((u >> 16) & 1u)) >> 16;  // RNE
  return (u16)r;
}
static __device__ __forceinline__ u32 pk2(float a, float b) {
  return (u32)f2bf(a) | ((u32)f2bf(b) << 16);
}

static __device__ __forceinline__ void gload_lds16(const u16* g, u16* l) {
  // async global->LDS, 16B per lane; LDS dest = wave-uniform base + lane*16
  __builtin_amdgcn_global_load_lds(
      (const __attribute__((address_space(1))) u32*)g,
      (__attribute__((address_space(3))) u32*)l, 16, 0, 0);
}

// ---------------- zero segment counters ----------------
__global__ void zero_kernel(int* cntE, int* cntV) {
  int i = blockIdx.x * 256 + threadIdx.x;
  if (i < NE) cntE[i] = 0;
  if (i < NV) cntV[i] = 0;
}

// ---------------- histogram of incidence pairs ----------------
__global__ void hist_kernel(const int* __restrict__ vidx, const int* __restrict__ eidx,
                            int* cntE, int* cntV) {
  int i = blockIdx.x * 256 + threadIdx.x;
  if (i < NNZp) {
    atomicAdd(&cntE[eidx[i]], 1);
    atomicAdd(&cntV[vidx[i]], 1);
  }
}

// ---------------- scan pass 1: per-block (1024 elems) local exclusive scan -----------
__global__ __launch_bounds__(256) void scan1_kernel(
    const int* __restrict__ cntE, const int* __restrict__ cntV,
    int* offE, int* offV, int* blkSum) {
  const bool isE = blockIdx.x < NBE;
  const int* cnt = isE ? cntE : cntV;
  int* off = isE ? offE : offV;
  const int len = isE ? NE : NV;
  const int t = threadIdx.x;
  const int base = (isE ? blockIdx.x : blockIdx.x - NBE) * 1024 + t * 4;
  int4 c = {0, 0, 0, 0};
  if (base + 4 <= len) c = *(const int4*)(cnt + base);
  else {
    if (base + 0 < len) c.x = cnt[base + 0];
    if (base + 1 < len) c.y = cnt[base + 1];
    if (base + 2 < len) c.z = cnt[base + 2];
    if (base + 3 < len) c.w = cnt[base + 3];
  }
  int s = c.x + c.y + c.z + c.w;
  __shared__ int sm[256];
  sm[t] = s;
  __syncthreads();
  for (int d = 1; d < 256; d <<= 1) {
    int u = (t >= d) ? sm[t - d] : 0;
    __syncthreads();
    sm[t] += u;
    __syncthreads();
  }
  int ex = sm[t] - s;  // exclusive prefix within block
  int4 o;
  o.x = ex; o.y = o.x + c.x; o.z = o.y + c.y; o.w = o.z + c.z;
  if (base + 4 <= len) *(int4*)(off + base) = o;
  else {
    if (base + 0 < len) off[base + 0] = o.x;
    if (base + 1 < len) off[base + 1] = o.y;
    if (base + 2 < len) off[base + 2] = o.z;
    if (base + 3 < len) off[base + 3] = o.w;
  }
  if (t == 255) blkSum[blockIdx.x] = sm[255];
}

// ---------------- scan pass 2: wave-scan the 25+49 block sums (in-place, exclusive) --
__global__ void scan2_kernel(int* blkSum) {
  int wv = threadIdx.x >> 6, lane = threadIdx.x & 63;
  int off = wv ? NBE : 0, len = wv ? NBV : NBE;
  int v = (lane < len) ? blkSum[off + lane] : 0;
  int incl = v;
#pragma unroll
  for (int d = 1; d < 64; d <<= 1) {
    int u = __shfl_up(incl, d, 64);
    if (lane >= d) incl += u;
  }
  if (lane < len) blkSum[off + lane] = incl - v;
}

// ---------------- scan pass 3: add block prefixes, materialize off & cur -------------
__global__ __launch_bounds__(256) void scan3_kernel(
    int* offE, int* offV, int* curE, int* curV, const int* __restrict__ blkSum) {
  const bool isE = blockIdx.x < NBE;
  int* off = isE ? offE : offV;
  int* cur = isE ? curE : curV;
  const int len = isE ? NE : NV;
  const int pref = blkSum[blockIdx.x];
  const int base = (isE ? blockIdx.x : blockIdx.x - NBE) * 1024 + threadIdx.x * 4;
  if (base + 4 <= len) {
    int4 o = *(int4*)(off + base);
    o.x += pref; o.y += pref; o.z += pref; o.w += pref;
    *(int4*)(off + base) = o;
    *(int4*)(cur + base) = o;
  } else {
    for (int q = 0; q < 4; q++)
      if (base + q < len) { int v = off[base + q] + pref; off[base + q] = v; cur[base + q] = v; }
  }
}

// ---------------- scatter pairs into CSR ----------------
__global__ void scatter_kernel(const int* __restrict__ vidx, const int* __restrict__ eidx,
                               int* curE, int* curV, int* csr_ev, int* csr_ve) {
  int i = blockIdx.x * 256 + threadIdx.x;
  if (i < NNZp) {
    int e = eidx[i], v = vidx[i];
    csr_ev[atomicAdd(&curE[e], 1)] = v;  // edge -> member vertices
    csr_ve[atomicAdd(&curV[v], 1)] = e;  // vertex -> incident edges
  }
}

// ---------------- fp32 -> bf16 convert (X then W, one grid) --------------------------
__global__ __launch_bounds__(256) void convert_kernel(
    const float* __restrict__ X, const float* __restrict__ W,
    u16* __restrict__ Xb, u16* __restrict__ Wb) {
  constexpr size_t NX = (size_t)NV * D;  // 25,600,000 (divisible by 8)
  size_t i = ((size_t)blockIdx.x * 256 + threadIdx.x) * 8;
  const float* src;
  u16* dst;
  if (i < NX) { src = X + i; dst = Xb + i; }
  else        { src = W + (i - NX); dst = Wb + (i - NX); }  // grid sized exactly
  f32x4 a = *(const f32x4*)src;
  f32x4 b = *(const f32x4*)(src + 4);
  u32x4 p = { pk2(a[0], a[1]), pk2(a[2], a[3]), pk2(b[0], b[1]), pk2(b[2], b[3]) };
  *(u32x4*)dst = p;
}

// ---------------- GEMM: Xp = Xb @ Wb^T, bf16 MFMA, global_load_lds staging -----------
// 128x128 tile, BK=32, 4 waves of 64x64, 16x16x32 MFMA (m97 structure).
__global__ __launch_bounds__(256) void gemm_kernel(const u16* __restrict__ A,
                                                   const u16* __restrict__ B,
                                                   u16* __restrict__ C) {
  __shared__ u16 sA[128 * 32];
  __shared__ u16 sB[128 * 32];
  const int tid  = threadIdx.x;
  const int lane = tid & 63;
  const int wave = tid >> 6;
  const int bm = blockIdx.y * 128;
  const int bn = blockIdx.x * 128;
  const int wm = (wave >> 1) * 64;
  const int wn = (wave & 1) * 64;
  const int lr = lane & 15;
  const int lk = (lane >> 4) * 8;
  const int srow = lane >> 2;        // 0..15: row within 16-row staging stripe
  const int scol = (lane & 3) * 8;   // 0/8/16/24: k-elem offset (16B)

  f32x4 acc[4][4] = {};

  for (int kt = 0; kt < D; kt += 32) {
    __syncthreads();  // previous iteration's LDS readers done
#pragma unroll
    for (int c = 0; c < 2; c++) {
      const int ar = wave * 16 + c * 64;          // wave-uniform stripe base row
      gload_lds16(A + (size_t)(bm + ar + srow) * D + kt + scol, &sA[ar * 32]);
      gload_lds16(B + (size_t)(bn + ar + srow) * D + kt + scol, &sB[ar * 32]);
    }
    __syncthreads();  // drains vmcnt: staging complete

    bf16x8 af[4], bfr[4];
#pragma unroll
    for (int i = 0; i < 4; i++) af[i]  = *(const bf16x8*)&sA[(wm + i * 16 + lr) * 32 + lk];
#pragma unroll
    for (int j = 0; j < 4; j++) bfr[j] = *(const bf16x8*)&sB[(wn + j * 16 + lr) * 32 + lk];
#pragma unroll
    for (int i = 0; i < 4; i++)
#pragma unroll
      for (int j = 0; j < 4; j++)
        acc[i][j] = __builtin_amdgcn_mfma_f32_16x16x32_bf16(af[i], bfr[j], acc[i][j], 0, 0, 0);
  }

  // C/D layout (16x16): col = lane&15, row = (lane>>4)*4 + reg
#pragma unroll
  for (int i = 0; i < 4; i++)
#pragma unroll
    for (int r = 0; r < 4; r++) {
      int row = bm + wm + i * 16 + (lane >> 4) * 4 + r;
      u16* crow = C + (size_t)row * D + bn + wn + lr;
#pragma unroll
      for (int j = 0; j < 4; j++) crow[j * 16] = f2bf(acc[i][j][r]);
    }
}

// ---------------- stage 1: vertex -> hyperedge, one WAVE per edge --------------------
__global__ __launch_bounds__(256) void stage1_kernel(
    const u16* __restrict__ Xp, const int* __restrict__ offE, const int* __restrict__ cntE,
    const int* __restrict__ csr_ev, const float* __restrict__ degE,
    const float* __restrict__ Wdiag, u16* __restrict__ Xe) {
  const int lane = threadIdx.x & 63;
  const int e = blockIdx.x * 4 + (threadIdx.x >> 6);
  const int start = offE[e], cnt = cntE[e];
  float acc[8] = {};
  for (int base = 0; base < cnt; base += 64) {
    int n = min(64, cnt - base);
    int myidx = (base + lane < cnt) ? csr_ev[start + base + lane] : 0;
#pragma unroll 4
    for (int k = 0; k < n; k++) {
      int v = __shfl(myidx, k, 64);
      u32x4 p = *(const u32x4*)(Xp + (size_t)v * D + lane * 8);
#pragma unroll
      for (int q = 0; q < 4; q++) {
        u32 u = p[q];
        acc[2 * q]     += __uint_as_float(u << 16);
        acc[2 * q + 1] += __uint_as_float(u & 0xffff0000u);
      }
    }
  }
  float s = degE[e] * Wdiag[e];
  u32x4 o = { pk2(acc[0] * s, acc[1] * s), pk2(acc[2] * s, acc[3] * s),
              pk2(acc[4] * s, acc[5] * s), pk2(acc[6] * s, acc[7] * s) };
  *(u32x4*)(Xe + (size_t)e * D + lane * 8) = o;
}

// ---------------- stage 2: hyperedge -> vertex, one WAVE per vertex ------------------
__global__ __launch_bounds__(256) void stage2_kernel(
    const u16* __restrict__ Xe, const int* __restrict__ offV, const int* __restrict__ cntV,
    const int* __restrict__ csr_ve, const float* __restrict__ degV, float* __restrict__ out) {
  const int lane = threadIdx.x & 63;
  const int v = blockIdx.x * 4 + (threadIdx.x >> 6);
  const int start = offV[v], cnt = cntV[v];
  float acc[8] = {};
  for (int base = 0; base < cnt; base += 64) {
    int n = min(64, cnt - base);
    int myidx = (base + lane < cnt) ? csr_ve[start + base + lane] : 0;
#pragma unroll 4
    for (int k = 0; k < n; k++) {
      int e = __shfl(myidx, k, 64);
      u32x4 p = *(const u32x4*)(Xe + (size_t)e * D + lane * 8);
#pragma unroll
      for (int q = 0; q < 4; q++) {
        u32 u = p[q];
        acc[2 * q]     += __uint_as_float(u << 16);
        acc[2 * q + 1] += __uint_as_float(u & 0xffff0000u);
      }
    }
  }
  float s = degV[v];
  float* orow = out + (size_t)v * D + lane * 8;
  f32x4 o0 = { acc[0] * s, acc[1] * s, acc[2] * s, acc[3] * s };
  f32x4 o1 = { acc[4] * s, acc[5] * s, acc[6] * s, acc[7] * s };
  *(f32x4*)orow = o0;
  *(f32x4*)(orow + 4) = o1;
}

extern "C" void kernel_launch(void* const* d_in, const int* in_sizes, int n_in,
                              void* d_out, int out_size, void* d_ws, size_t ws_size,
                              hipStream_t stream) {
  const float* X     = (const float*)d_in[0];
  const float* W     = (const float*)d_in[1];
  const float* degE  = (const float*)d_in[2];
  const float* degV  = (const float*)d_in[3];
  const float* Wdiag = (const float*)d_in[4];
  const int*   vidx  = (const int*)d_in[5];
  const int*   eidx  = (const int*)d_in[6];
  float* out = (float*)d_out;

  // workspace carve (all 256B aligned); total ~82 MB
  char* p = (char*)d_ws;
  auto take = [&](size_t bytes) { char* r = p; p += (bytes + 255) & ~(size_t)255; return r; };
  u16* Xb     = (u16*)take((size_t)MP * D * 2);   // bf16 X (rows >= NV unused garbage)
  u16* Wb     = (u16*)take((size_t)D * D * 2);    // bf16 W
  u16* Xp     = (u16*)take((size_t)MP * D * 2);   // bf16 projected features
  u16* Xe     = (u16*)take((size_t)NE * D * 2);   // bf16 edge features
  int* cntE   = (int*)take((size_t)NE * 4);
  int* offE   = (int*)take((size_t)NE * 4);
  int* curE   = (int*)take((size_t)NE * 4);
  int* cntV   = (int*)take((size_t)NV * 4);
  int* offV   = (int*)take((size_t)NV * 4);
  int* curV   = (int*)take((size_t)NV * 4);
  int* csr_ev = (int*)take((size_t)NNZp * 4);
  int* csr_ve = (int*)take((size_t)NNZp * 4);
  int* blkSum = (int*)take((size_t)(NBE + NBV) * 4);

  constexpr size_t NCONV = ((size_t)NV * D + (size_t)D * D) / 8 / 256;  // 12628 exact

  zero_kernel   <<<(NV + 255) / 256, 256, 0, stream>>>(cntE, cntV);
  hist_kernel   <<<(NNZp + 255) / 256, 256, 0, stream>>>(vidx, eidx, cntE, cntV);
  scan1_kernel  <<<NBE + NBV, 256, 0, stream>>>(cntE, cntV, offE, offV, blkSum);
  scan2_kernel  <<<1, 128, 0, stream>>>(blkSum);
  scan3_kernel  <<<NBE + NBV, 256, 0, stream>>>(offE, offV, curE, curV, blkSum);
  scatter_kernel<<<(NNZp + 255) / 256, 256, 0, stream>>>(vidx, eidx, curE, curV, csr_ev, csr_ve);
  convert_kernel<<<NCONV, 256, 0, stream>>>(X, W, Xb, Wb);
  gemm_kernel   <<<dim3(D / 128, MP / 128), 256, 0, stream>>>(Xb, Wb, Xp);
  stage1_kernel <<<NE / 4, 256, 0, stream>>>(Xp, offE, cntE, csr_ev, degE, Wdiag, Xe);
  stage2_kernel <<<NV / 4, 256, 0, stream>>>(Xe, offV, cntV, csr_ve, degV, out);
}